// Round 1
// baseline (524.532 us; speedup 1.0000x reference)
//
#include <hip/hip_runtime.h>

#define N_S   4096
#define NTOT  8192
#define D     256
#define BM    64
#define BK    16
#define LDT   68          // padded LDS row stride (4*68 mod 32 = 16 -> worst 2..4-way on store only)
#define GRID1 128         // 8192 / BM

// ---- workspace layout (bytes). Everything fully overwritten every launch. ----
#define WS_SQ        0                              // 8192 f32      (32 KB)
#define WS_COLPART   (32*1024)                      // 64*256 f64    (128 KB)
#define WS_SQPART    (WS_COLPART + 64*256*8)        // 64 f64
#define WS_COEF      (WS_SQPART + 64*8)             // 5 f32 (padded to 32 B)
#define WS_QUADPART  (WS_COEF + 32)                 // 16384 f64     (128 KB)

// ---------------------------------------------------------------------------
// Kernel A: per-row sum-of-squares sq[i], per-block column sums (f64) and
// per-block sum of sq (f64). 64 blocks x 256 threads; block b owns 128 rows.
// ---------------------------------------------------------------------------
__global__ __launch_bounds__(256) void rowstats_kernel(
    const float* __restrict__ src, const float* __restrict__ tgt,
    float* __restrict__ sq, double* __restrict__ colpart,
    double* __restrict__ sqpart)
{
    const int b    = blockIdx.x;
    const int tid  = threadIdx.x;
    const int w    = tid >> 6;
    const int lane = tid & 63;
    const int row0 = b * 128 + w * 32;                    // 32 rows per wave
    const float* base = (row0 < N_S) ? (src + (size_t)row0 * D)
                                     : (tgt + (size_t)(row0 - N_S) * D);
    double colacc0 = 0.0, colacc1 = 0.0, colacc2 = 0.0, colacc3 = 0.0;
    double wavesq  = 0.0;
    for (int r = 0; r < 32; ++r) {
        const float4 v = *(const float4*)(base + (size_t)r * D + lane * 4);
        float s = v.x * v.x + v.y * v.y + v.z * v.z + v.w * v.w;
        colacc0 += (double)v.x; colacc1 += (double)v.y;
        colacc2 += (double)v.z; colacc3 += (double)v.w;
        #pragma unroll
        for (int off = 32; off; off >>= 1) s += __shfl_xor(s, off, 64);
        if (lane == 0) sq[row0 + r] = s;
        wavesq += (double)s;                              // same value on all lanes
    }
    __shared__ double cp[4][256];
    __shared__ double sqw[4];
    cp[w][lane * 4 + 0] = colacc0;
    cp[w][lane * 4 + 1] = colacc1;
    cp[w][lane * 4 + 2] = colacc2;
    cp[w][lane * 4 + 3] = colacc3;
    if (lane == 0) sqw[w] = wavesq;
    __syncthreads();
    colpart[b * 256 + tid] = cp[0][tid] + cp[1][tid] + cp[2][tid] + cp[3][tid];
    if (tid == 0) sqpart[b] = sqw[0] + sqw[1] + sqw[2] + sqw[3];
}

// ---------------------------------------------------------------------------
// Kernel B: bandwidth (analytic, fp64) -> exp2 coefficients c2[i] = log2(e)/(bw*2^i)
// ---------------------------------------------------------------------------
__global__ __launch_bounds__(256) void bandwidth_kernel(
    const double* __restrict__ colpart, const double* __restrict__ sqpart,
    float* __restrict__ coef)
{
    const int tid = threadIdx.x;
    double cs = 0.0;
    for (int b = 0; b < 64; ++b) cs += colpart[b * 256 + tid];
    double v = cs * cs;
    #pragma unroll
    for (int off = 32; off; off >>= 1) v += __shfl_xor(v, off, 64);
    __shared__ double part[4];
    if ((tid & 63) == 0) part[tid >> 6] = v;
    __syncthreads();
    if (tid == 0) {
        double s2 = part[0] + part[1] + part[2] + part[3];  // || sum_i x_i ||^2
        double sumsq = 0.0;
        for (int b = 0; b < 64; ++b) sumsq += sqpart[b];
        const double n = (double)NTOT;
        double bwsum = 2.0 * n * sumsq - 2.0 * s2;          // sum_ij L2_ij
        double bandwidth = bwsum / (n * n - n);
        bandwidth *= 0.25;                                  // / KERNEL_MUL^(5//2)
        const double LOG2E = 1.4426950408889634;
        double m = 1.0;
        for (int i = 0; i < 5; ++i) { coef[i] = (float)(LOG2E / (bandwidth * m)); m *= 2.0; }
    }
}

// ---------------------------------------------------------------------------
// Kernel C (main): tiled pairwise L2 + fused 5-exp kernel sum.
// Grid (128,128), 256 threads, 64x64 tile, 4x4 per-thread microtile, BK=16.
// One fp64 partial per block -> quadpart[by*128+bx].
// ---------------------------------------------------------------------------
__global__ __launch_bounds__(256) void mmd_main_kernel(
    const float* __restrict__ src, const float* __restrict__ tgt,
    const float* __restrict__ sq, const float* __restrict__ coef,
    double* __restrict__ quadpart)
{
    __shared__ float Ast[BK][LDT];
    __shared__ float Bst[BK][LDT];
    __shared__ double wpart[4];

    const int bx = blockIdx.x, by = blockIdx.y;
    const int tid = threadIdx.x;
    const int tx = tid & 15, ty = tid >> 4;
    const int rowA0 = by * BM, rowB0 = bx * BM;
    const float* Abase = (rowA0 < N_S) ? (src + (size_t)rowA0 * D)
                                       : (tgt + (size_t)(rowA0 - N_S) * D);
    const float* Bbase = (rowB0 < N_S) ? (src + (size_t)rowB0 * D)
                                       : (tgt + (size_t)(rowB0 - N_S) * D);
    const float c0 = coef[0], c1 = coef[1], c2 = coef[2], c3 = coef[3], c4 = coef[4];

    float acc[4][4] = {};
    const int lrow = tid >> 2;   // 0..63
    const int lk4  = tid & 3;    // 0..3

    for (int kk = 0; kk < D; kk += BK) {
        const float4 a = *(const float4*)(Abase + (size_t)lrow * D + kk + lk4 * 4);
        const float4 b = *(const float4*)(Bbase + (size_t)lrow * D + kk + lk4 * 4);
        Ast[lk4 * 4 + 0][lrow] = a.x; Ast[lk4 * 4 + 1][lrow] = a.y;
        Ast[lk4 * 4 + 2][lrow] = a.z; Ast[lk4 * 4 + 3][lrow] = a.w;
        Bst[lk4 * 4 + 0][lrow] = b.x; Bst[lk4 * 4 + 1][lrow] = b.y;
        Bst[lk4 * 4 + 2][lrow] = b.z; Bst[lk4 * 4 + 3][lrow] = b.w;
        __syncthreads();
        #pragma unroll
        for (int k = 0; k < BK; ++k) {
            const float4 av = *(const float4*)&Ast[k][ty * 4];
            const float4 bv = *(const float4*)&Bst[k][tx * 4];
            const float am[4] = {av.x, av.y, av.z, av.w};
            const float bn[4] = {bv.x, bv.y, bv.z, bv.w};
            #pragma unroll
            for (int mm = 0; mm < 4; ++mm)
                #pragma unroll
                for (int nn = 0; nn < 4; ++nn)
                    acc[mm][nn] = fmaf(am[mm], bn[nn], acc[mm][nn]);
        }
        __syncthreads();
    }

    float sqa[4], sqb[4];
    #pragma unroll
    for (int mm = 0; mm < 4; ++mm) sqa[mm] = sq[rowA0 + ty * 4 + mm];
    #pragma unroll
    for (int nn = 0; nn < 4; ++nn) sqb[nn] = sq[rowB0 + tx * 4 + nn];

    float ks = 0.0f;
    #pragma unroll
    for (int mm = 0; mm < 4; ++mm) {
        #pragma unroll
        for (int nn = 0; nn < 4; ++nn) {
            float l2 = fmaxf(sqa[mm] + sqb[nn] - 2.0f * acc[mm][nn], 0.0f);
            const float t = -l2;
            ks += __builtin_amdgcn_exp2f(t * c0) + __builtin_amdgcn_exp2f(t * c1)
                + __builtin_amdgcn_exp2f(t * c2) + __builtin_amdgcn_exp2f(t * c3)
                + __builtin_amdgcn_exp2f(t * c4);
        }
    }

    double v = (double)ks;
    #pragma unroll
    for (int off = 32; off; off >>= 1) v += __shfl_xor(v, off, 64);
    if ((tid & 63) == 0) wpart[tid >> 6] = v;
    __syncthreads();
    if (tid == 0) quadpart[by * GRID1 + bx] = wpart[0] + wpart[1] + wpart[2] + wpart[3];
}

// ---------------------------------------------------------------------------
// Kernel D: final reduction over 16384 block partials -> scalar.
// ---------------------------------------------------------------------------
__global__ __launch_bounds__(256) void finalize_kernel(
    const double* __restrict__ quadpart, float* __restrict__ out)
{
    const int tid = threadIdx.x;
    double acc[4] = {0.0, 0.0, 0.0, 0.0};
    for (int i = tid; i < GRID1 * GRID1; i += 256) {
        const int by = i >> 7, bx = i & 127;
        const int q = ((by >= 64) ? 2 : 0) + ((bx >= 64) ? 1 : 0);
        acc[q] += quadpart[i];
    }
    #pragma unroll
    for (int q = 0; q < 4; ++q)
        #pragma unroll
        for (int off = 32; off; off >>= 1) acc[q] += __shfl_xor(acc[q], off, 64);
    __shared__ double part[4][4];
    const int w = tid >> 6, lane = tid & 63;
    if (lane == 0) {
        #pragma unroll
        for (int q = 0; q < 4; ++q) part[w][q] = acc[q];
    }
    __syncthreads();
    if (tid == 0) {
        double s[4];
        #pragma unroll
        for (int q = 0; q < 4; ++q) s[q] = part[0][q] + part[1][q] + part[2][q] + part[3][q];
        // out = mean(SS) + mean(TT) - 2*mean(ST); cross (q=1 and q=2) sums = ST + TS = 2*ST
        const double denom = (double)N_S * (double)N_S;
        const double res = (s[0] + s[3] - s[1] - s[2]) / denom;
        out[0] = (float)res;
    }
}

extern "C" void kernel_launch(void* const* d_in, const int* in_sizes, int n_in,
                              void* d_out, int out_size, void* d_ws, size_t ws_size,
                              hipStream_t stream)
{
    const float* src = (const float*)d_in[0];
    const float* tgt = (const float*)d_in[1];
    float*  out      = (float*)d_out;
    char*   ws       = (char*)d_ws;

    float*  sq       = (float*)(ws + WS_SQ);
    double* colpart  = (double*)(ws + WS_COLPART);
    double* sqpart   = (double*)(ws + WS_SQPART);
    float*  coef     = (float*)(ws + WS_COEF);
    double* quadpart = (double*)(ws + WS_QUADPART);

    rowstats_kernel<<<64, 256, 0, stream>>>(src, tgt, sq, colpart, sqpart);
    bandwidth_kernel<<<1, 256, 0, stream>>>(colpart, sqpart, coef);
    mmd_main_kernel<<<dim3(GRID1, GRID1), 256, 0, stream>>>(src, tgt, sq, coef, quadpart);
    finalize_kernel<<<1, 256, 0, stream>>>(quadpart, out);
}

// Round 2
// 118.051 us; speedup vs baseline: 4.4433x; 4.4433x over previous
//
#include <hip/hip_runtime.h>
#include <stdint.h>

#define N_S   4096
#define NTOT  8192
#define D     256

typedef __attribute__((ext_vector_type(8))) short short8v;      // 8 bf16 (4 VGPR)
typedef __attribute__((ext_vector_type(4))) float f32x4;        // MFMA acc
typedef __attribute__((ext_vector_type(8))) unsigned short ushort8v;

// ---- workspace layout (bytes). Everything fully overwritten every launch. ----
#define WS_SQ        0                         // 8192 f32  (32 KB)
#define WS_COLPART   32768                     // 64*256 f64 (128 KB)
#define WS_SQPART    163840                    // 64 f64
#define WS_COEF      164352                    // 5 f32
#define WS_QUADPART  172032                    // up to 16384 f64 (128 KB)
#define WS_XHI       524288                    // 4 MB  bf16 hi, panel/slot-major
#define WS_XLO       (524288 + 4194304)        // 4 MB  bf16 lo
#define WS_NEED_MFMA ((size_t)(WS_XLO) + 4194304)

// ---------------------------------------------------------------------------
// rowstats: per-row sum-of-squares sq[i] (exact fp32 inputs), per-block column
// sums (f64) and per-block sum of sq (f64) for the analytic bandwidth.
// ---------------------------------------------------------------------------
__global__ __launch_bounds__(256) void rowstats_kernel(
    const float* __restrict__ src, const float* __restrict__ tgt,
    float* __restrict__ sq, double* __restrict__ colpart,
    double* __restrict__ sqpart)
{
    const int b    = blockIdx.x;
    const int tid  = threadIdx.x;
    const int w    = tid >> 6;
    const int lane = tid & 63;
    const int row0 = b * 128 + w * 32;
    const float* base = (row0 < N_S) ? (src + (size_t)row0 * D)
                                     : (tgt + (size_t)(row0 - N_S) * D);
    double colacc0 = 0.0, colacc1 = 0.0, colacc2 = 0.0, colacc3 = 0.0;
    double wavesq  = 0.0;
    for (int r = 0; r < 32; ++r) {
        const float4 v = *(const float4*)(base + (size_t)r * D + lane * 4);
        float s = v.x * v.x + v.y * v.y + v.z * v.z + v.w * v.w;
        colacc0 += (double)v.x; colacc1 += (double)v.y;
        colacc2 += (double)v.z; colacc3 += (double)v.w;
        #pragma unroll
        for (int off = 32; off; off >>= 1) s += __shfl_xor(s, off, 64);
        if (lane == 0) sq[row0 + r] = s;
        wavesq += (double)s;
    }
    __shared__ double cp[4][256];
    __shared__ double sqw[4];
    cp[w][lane * 4 + 0] = colacc0;
    cp[w][lane * 4 + 1] = colacc1;
    cp[w][lane * 4 + 2] = colacc2;
    cp[w][lane * 4 + 3] = colacc3;
    if (lane == 0) sqw[w] = wavesq;
    __syncthreads();
    colpart[b * 256 + tid] = cp[0][tid] + cp[1][tid] + cp[2][tid] + cp[3][tid];
    if (tid == 0) sqpart[b] = sqw[0] + sqw[1] + sqw[2] + sqw[3];
}

// ---------------------------------------------------------------------------
// bandwidth: analytic fp64 sum(L2) -> exp2 coefficients coef[i]=log2e/(bw*2^i)
// ---------------------------------------------------------------------------
__global__ __launch_bounds__(256) void bandwidth_kernel(
    const double* __restrict__ colpart, const double* __restrict__ sqpart,
    float* __restrict__ coef)
{
    const int tid = threadIdx.x;
    double cs = 0.0;
    for (int b = 0; b < 64; ++b) cs += colpart[b * 256 + tid];
    double v = cs * cs;
    #pragma unroll
    for (int off = 32; off; off >>= 1) v += __shfl_xor(v, off, 64);
    __shared__ double part[4];
    if ((tid & 63) == 0) part[tid >> 6] = v;
    __syncthreads();
    if (tid == 0) {
        double s2 = part[0] + part[1] + part[2] + part[3];
        double sumsq = 0.0;
        for (int b = 0; b < 64; ++b) sumsq += sqpart[b];
        const double n = (double)NTOT;
        double bwsum = 2.0 * n * sumsq - 2.0 * s2;
        double bandwidth = bwsum / (n * n - n);
        bandwidth *= 0.25;
        const double LOG2E = 1.4426950408889634;
        double m = 1.0;
        for (int i = 0; i < 5; ++i) { coef[i] = (float)(LOG2E / (bandwidth * m)); m *= 2.0; }
    }
}

// ---------------------------------------------------------------------------
// convert: fp32 X -> bf16 hi/lo, written in staged panel layout:
// byte = ((kt*64 + p) * 8192) + u*2048 + r*16
//   kt: k-tile (32 elems), p: 128-row panel, u: k-slot (8 elems), r: row in panel
// This makes main-kernel staging contiguous and LDS frag reads conflict-free.
// ---------------------------------------------------------------------------
__global__ __launch_bounds__(256) void convert_kernel(
    const float* __restrict__ src, const float* __restrict__ tgt,
    char* __restrict__ xhi, char* __restrict__ xlo)
{
    const int g = blockIdx.x * 256 + threadIdx.x;   // 262144 granules of 16B
    const int r  = g & 127;
    const int u  = (g >> 7) & 3;
    const int p  = (g >> 9) & 63;
    const int kt = g >> 15;
    const int R  = p * 128 + r;
    const float* base = (R < N_S) ? (src + (size_t)R * D)
                                  : (tgt + (size_t)(R - N_S) * D);
    const float* xp = base + kt * 32 + u * 8;
    const float4 v0 = *(const float4*)xp;
    const float4 v1 = *(const float4*)(xp + 4);
    const float xs[8] = {v0.x, v0.y, v0.z, v0.w, v1.x, v1.y, v1.z, v1.w};
    ushort8v h, l;
    #pragma unroll
    for (int j = 0; j < 8; ++j) {
        const uint32_t b  = __float_as_uint(xs[j]);
        const uint32_t rh = (b + 0x7FFFu + ((b >> 16) & 1u)) >> 16;     // RNE bf16
        const float hf = __uint_as_float(rh << 16);
        const float lf = xs[j] - hf;                                    // exact
        const uint32_t bl = __float_as_uint(lf);
        h[j] = (unsigned short)rh;
        l[j] = (unsigned short)((bl + 0x7FFFu + ((bl >> 16) & 1u)) >> 16);
    }
    const size_t off = (size_t)g * 16;
    *(ushort8v*)(xhi + off) = h;
    *(ushort8v*)(xlo + off) = l;
}

// ---------------------------------------------------------------------------
// main (MFMA): symmetric 128x128 tiles, 4 waves each 64x64 output,
// 16x16x32 bf16 MFMA, split-3 products (hi*hi + hi*lo + lo*hi).
// LDS: [2 buf][Ahi,Alo,Bhi,Blo][8KB], slot-major (u*2048 + row*16) per buffer.
// ---------------------------------------------------------------------------
__global__ __launch_bounds__(256) void mmd_mfma_kernel(
    const char* __restrict__ xhi, const char* __restrict__ xlo,
    const float* __restrict__ sq, const float* __restrict__ coef,
    double* __restrict__ quadpart)
{
    const int by = blockIdx.y, bx = blockIdx.x;
    if (bx < by) return;                    // symmetry: upper triangle only

    __shared__ char lds[2][4][8192];        // 64 KB
    const int tid  = threadIdx.x;
    const int w    = tid >> 6;
    const int lane = tid & 63;
    const int wr   = w >> 1, wc = w & 1;    // 2x2 wave grid, 64x64 each

    const float c0 = coef[0], c1 = coef[1], c2 = coef[2], c3 = coef[3], c4 = coef[4];

    // staging: wave w copies one array per k-tile (w0:Ahi w1:Alo w2:Bhi w3:Blo)
    const char* psrc  = (w & 1) ? xlo : xhi;
    const int   panel = (w < 2) ? by : bx;

    typedef const __attribute__((address_space(1))) void* gp_t;
    typedef __attribute__((address_space(3))) void* lp_t;

    auto STAGE = [&](int buf, int kt) {
        const char* s = psrc + (((size_t)(kt * 64 + panel)) << 13) + lane * 16;
        char* d = &lds[buf][w][0];
        #pragma unroll
        for (int i = 0; i < 8; ++i) {
            __builtin_amdgcn_global_load_lds((gp_t)(uintptr_t)(s + i * 1024),
                                             (lp_t)(uintptr_t)(d + i * 1024),
                                             16, 0, 0);
        }
    };

    f32x4 acc[4][4];
    #pragma unroll
    for (int m = 0; m < 4; ++m)
        #pragma unroll
        for (int n = 0; n < 4; ++n)
            acc[m][n] = (f32x4){0.0f, 0.0f, 0.0f, 0.0f};

    const int grp  = lane >> 4;                       // k-slot 0..3
    const int r16  = lane & 15;
    const int aoff = grp * 2048 + (wr * 64 + r16) * 16;
    const int boff = grp * 2048 + (wc * 64 + r16) * 16;

    STAGE(0, 0);
    __syncthreads();
    for (int kt = 0; kt < 8; ++kt) {
        if (kt < 7) STAGE((kt + 1) & 1, kt + 1);
        const char* Ah = &lds[kt & 1][0][0];
        const char* Al = &lds[kt & 1][1][0];
        const char* Bh = &lds[kt & 1][2][0];
        const char* Bl = &lds[kt & 1][3][0];
        short8v ah[4], al[4], bh[4], bl[4];
        #pragma unroll
        for (int t = 0; t < 4; ++t) {                 // 16-row sub-tiles: +256B
            ah[t] = *(const short8v*)(Ah + aoff + t * 256);
            al[t] = *(const short8v*)(Al + aoff + t * 256);
            bh[t] = *(const short8v*)(Bh + boff + t * 256);
            bl[t] = *(const short8v*)(Bl + boff + t * 256);
        }
        #pragma unroll
        for (int m = 0; m < 4; ++m)
            #pragma unroll
            for (int n = 0; n < 4; ++n) {
                acc[m][n] = __builtin_amdgcn_mfma_f32_16x16x32_bf16(ah[m], bh[n], acc[m][n], 0, 0, 0);
                acc[m][n] = __builtin_amdgcn_mfma_f32_16x16x32_bf16(ah[m], bl[n], acc[m][n], 0, 0, 0);
                acc[m][n] = __builtin_amdgcn_mfma_f32_16x16x32_bf16(al[m], bh[n], acc[m][n], 0, 0, 0);
            }
        __syncthreads();
    }

    // epilogue: L2 -> 5-exp kernel sum. C layout: col=lane&15, row=(lane>>4)*4+reg
    double kd = 0.0;
    #pragma unroll
    for (int m = 0; m < 4; ++m) {
        float sqa[4];
        #pragma unroll
        for (int r = 0; r < 4; ++r)
            sqa[r] = sq[by * 128 + wr * 64 + m * 16 + grp * 4 + r];
        #pragma unroll
        for (int n = 0; n < 4; ++n) {
            const float sqb = sq[bx * 128 + wc * 64 + n * 16 + r16];
            float ks = 0.0f;
            #pragma unroll
            for (int r = 0; r < 4; ++r) {
                const float l2 = fmaxf(sqa[r] + sqb - 2.0f * acc[m][n][r], 0.0f);
                const float t = -l2;
                ks += __builtin_amdgcn_exp2f(t * c0) + __builtin_amdgcn_exp2f(t * c1)
                    + __builtin_amdgcn_exp2f(t * c2) + __builtin_amdgcn_exp2f(t * c3)
                    + __builtin_amdgcn_exp2f(t * c4);
            }
            kd += (double)ks;
        }
    }
    #pragma unroll
    for (int off = 32; off; off >>= 1) kd += __shfl_xor(kd, off, 64);
    double* wp = (double*)&lds[0][0][0];
    if (lane == 0) wp[w] = kd;
    __syncthreads();
    if (tid == 0) {
        const double s = wp[0] + wp[1] + wp[2] + wp[3];
        quadpart[by * 64 + bx] = s;
        if (bx > by) quadpart[bx * 64 + by] = s;   // mirror block
    }
}

// ---------------------------------------------------------------------------
// fallback main (pure fp32 vector path) — known-good from R1.
// ---------------------------------------------------------------------------
#define BK   16
#define LDT  68
__global__ __launch_bounds__(256) void mmd_main_kernel(
    const float* __restrict__ src, const float* __restrict__ tgt,
    const float* __restrict__ sq, const float* __restrict__ coef,
    double* __restrict__ quadpart)
{
    __shared__ float Ast[BK][LDT];
    __shared__ float Bst[BK][LDT];
    __shared__ double wpart[4];

    const int bx = blockIdx.x, by = blockIdx.y;
    const int tid = threadIdx.x;
    const int tx = tid & 15, ty = tid >> 4;
    const int rowA0 = by * 64, rowB0 = bx * 64;
    const float* Abase = (rowA0 < N_S) ? (src + (size_t)rowA0 * D)
                                       : (tgt + (size_t)(rowA0 - N_S) * D);
    const float* Bbase = (rowB0 < N_S) ? (src + (size_t)rowB0 * D)
                                       : (tgt + (size_t)(rowB0 - N_S) * D);
    const float c0 = coef[0], c1 = coef[1], c2 = coef[2], c3 = coef[3], c4 = coef[4];

    float acc[4][4] = {};
    const int lrow = tid >> 2;
    const int lk4  = tid & 3;

    for (int kk = 0; kk < D; kk += BK) {
        const float4 a = *(const float4*)(Abase + (size_t)lrow * D + kk + lk4 * 4);
        const float4 b = *(const float4*)(Bbase + (size_t)lrow * D + kk + lk4 * 4);
        Ast[lk4 * 4 + 0][lrow] = a.x; Ast[lk4 * 4 + 1][lrow] = a.y;
        Ast[lk4 * 4 + 2][lrow] = a.z; Ast[lk4 * 4 + 3][lrow] = a.w;
        Bst[lk4 * 4 + 0][lrow] = b.x; Bst[lk4 * 4 + 1][lrow] = b.y;
        Bst[lk4 * 4 + 2][lrow] = b.z; Bst[lk4 * 4 + 3][lrow] = b.w;
        __syncthreads();
        #pragma unroll
        for (int k = 0; k < BK; ++k) {
            const float4 av = *(const float4*)&Ast[k][ty * 4];
            const float4 bv = *(const float4*)&Bst[k][tx * 4];
            const float am[4] = {av.x, av.y, av.z, av.w};
            const float bn[4] = {bv.x, bv.y, bv.z, bv.w};
            #pragma unroll
            for (int mm = 0; mm < 4; ++mm)
                #pragma unroll
                for (int nn = 0; nn < 4; ++nn)
                    acc[mm][nn] = fmaf(am[mm], bn[nn], acc[mm][nn]);
        }
        __syncthreads();
    }

    float sqa[4], sqb[4];
    #pragma unroll
    for (int mm = 0; mm < 4; ++mm) sqa[mm] = sq[rowA0 + ty * 4 + mm];
    #pragma unroll
    for (int nn = 0; nn < 4; ++nn) sqb[nn] = sq[rowB0 + tx * 4 + nn];

    float ks = 0.0f;
    #pragma unroll
    for (int mm = 0; mm < 4; ++mm)
        #pragma unroll
        for (int nn = 0; nn < 4; ++nn) {
            const float l2 = fmaxf(sqa[mm] + sqb[nn] - 2.0f * acc[mm][nn], 0.0f);
            const float t = -l2;
            ks += __builtin_amdgcn_exp2f(t * c0) + __builtin_amdgcn_exp2f(t * c1)
                + __builtin_amdgcn_exp2f(t * c2) + __builtin_amdgcn_exp2f(t * c3)
                + __builtin_amdgcn_exp2f(t * c4);
        }

    double v = (double)ks;
    #pragma unroll
    for (int off = 32; off; off >>= 1) v += __shfl_xor(v, off, 64);
    if ((tid & 63) == 0) wpart[tid >> 6] = v;
    __syncthreads();
    if (tid == 0) quadpart[by * 128 + bx] = wpart[0] + wpart[1] + wpart[2] + wpart[3];
}

// ---------------------------------------------------------------------------
// finalize: reduce nb x nb block partials into the quadrant combination.
// ---------------------------------------------------------------------------
__global__ __launch_bounds__(256) void finalize_kernel(
    const double* __restrict__ quadpart, float* __restrict__ out, int nbshift)
{
    const int tid  = threadIdx.x;
    const int nb   = 1 << nbshift;
    const int half = nb >> 1;
    const int mask = nb - 1;
    const int tot  = nb * nb;
    double acc[4] = {0.0, 0.0, 0.0, 0.0};
    for (int i = tid; i < tot; i += 256) {
        const int by = i >> nbshift, bx = i & mask;
        const int q = ((by >= half) ? 2 : 0) + ((bx >= half) ? 1 : 0);
        acc[q] += quadpart[i];
    }
    #pragma unroll
    for (int q = 0; q < 4; ++q)
        #pragma unroll
        for (int off = 32; off; off >>= 1) acc[q] += __shfl_xor(acc[q], off, 64);
    __shared__ double part[4][4];
    const int w = tid >> 6, lane = tid & 63;
    if (lane == 0) {
        #pragma unroll
        for (int q = 0; q < 4; ++q) part[w][q] = acc[q];
    }
    __syncthreads();
    if (tid == 0) {
        double s[4];
        #pragma unroll
        for (int q = 0; q < 4; ++q) s[q] = part[0][q] + part[1][q] + part[2][q] + part[3][q];
        const double denom = (double)N_S * (double)N_S;
        out[0] = (float)((s[0] + s[3] - s[1] - s[2]) / denom);
    }
}

extern "C" void kernel_launch(void* const* d_in, const int* in_sizes, int n_in,
                              void* d_out, int out_size, void* d_ws, size_t ws_size,
                              hipStream_t stream)
{
    const float* src = (const float*)d_in[0];
    const float* tgt = (const float*)d_in[1];
    float*  out      = (float*)d_out;
    char*   ws       = (char*)d_ws;

    float*  sq       = (float*)(ws + WS_SQ);
    double* colpart  = (double*)(ws + WS_COLPART);
    double* sqpart   = (double*)(ws + WS_SQPART);
    float*  coef     = (float*)(ws + WS_COEF);
    double* quadpart = (double*)(ws + WS_QUADPART);
    char*   xhi      = ws + WS_XHI;
    char*   xlo      = ws + WS_XLO;

    rowstats_kernel<<<64, 256, 0, stream>>>(src, tgt, sq, colpart, sqpart);
    bandwidth_kernel<<<1, 256, 0, stream>>>(colpart, sqpart, coef);

    if (ws_size >= WS_NEED_MFMA) {
        convert_kernel<<<1024, 256, 0, stream>>>(src, tgt, xhi, xlo);
        mmd_mfma_kernel<<<dim3(64, 64), 256, 0, stream>>>(xhi, xlo, sq, coef, quadpart);
        finalize_kernel<<<1, 256, 0, stream>>>(quadpart, out, 6);
    } else {
        mmd_main_kernel<<<dim3(128, 128), 256, 0, stream>>>(src, tgt, sq, coef, quadpart);
        finalize_kernel<<<1, 256, 0, stream>>>(quadpart, out, 7);
    }
}

// Round 3
// 64.609 us; speedup vs baseline: 8.1186x; 1.8272x over previous
//
#include <hip/hip_runtime.h>
#include <hip/hip_fp16.h>
#include <stdint.h>

#define N_S   4096
#define NTOT  8192
#define D     256
#define NBLK  2080            // 64*65/2 triangular blocks of 128x128

typedef __attribute__((ext_vector_type(8))) short short8v;   // 8 fp16 (4 VGPR)
typedef __attribute__((ext_vector_type(4))) float f32x4;     // MFMA acc

// ---- workspace layout (bytes). Everything fully overwritten every launch. ----
#define WS_SQ        0                         // 8192 f32   (32 KB)
#define WS_COLPART   32768                     // 128*256 f64 (256 KB)
#define WS_SQPART    294912                    // 128 f64
#define WS_COEF      295936                    // 1 f32 (padded)
#define WS_QUADPART  296960                    // 4096 f64   (32 KB)
#define WS_XH        329728                    // 4 MB fp16, panel/slot-major

// ---------------------------------------------------------------------------
// prep: one pass over X. Produces (a) sq[i] = |x_i|^2 in exact fp32,
// (b) f64 per-block column sums + sum of sq (for analytic bandwidth),
// (c) fp16 conversion written in panel/slot-major layout:
//     byte = ((kt*64 + p) << 13) + u*2048 + rp*16 + half*8
//     kt = k-tile (32 elems), p = 128-row panel, u = 8-elem k-slot, rp = row.
// 128 blocks x 256 threads; wave handles 16 rows; lane owns 4 columns.
// ---------------------------------------------------------------------------
__global__ __launch_bounds__(256) void prep_kernel(
    const float* __restrict__ src, const float* __restrict__ tgt,
    float* __restrict__ sq, double* __restrict__ colpart,
    double* __restrict__ sqpart, char* __restrict__ xh)
{
    const int b    = blockIdx.x;
    const int tid  = threadIdx.x;
    const int w    = tid >> 6;
    const int lane = tid & 63;
    const int row0 = b * 64 + w * 16;
    const float* base = (row0 < N_S) ? (src + (size_t)row0 * D)
                                     : (tgt + (size_t)(row0 - N_S) * D);
    const int kt   = lane >> 3;          // 8 lanes per 32-elem k-tile
    const int u    = (lane >> 1) & 3;    // 8-elem k-slot
    const int half = lane & 1;           // which 8B half of the 16B granule

    double ca0 = 0.0, ca1 = 0.0, ca2 = 0.0, ca3 = 0.0;
    double wsq = 0.0;
    for (int r = 0; r < 16; ++r) {
        const int row = row0 + r;
        const float4 v = *(const float4*)(base + (size_t)r * D + lane * 4);
        float s = v.x * v.x + v.y * v.y + v.z * v.z + v.w * v.w;
        ca0 += (double)v.x; ca1 += (double)v.y;
        ca2 += (double)v.z; ca3 += (double)v.w;
        #pragma unroll
        for (int off = 32; off; off >>= 1) s += __shfl_xor(s, off, 64);
        if (lane == 0) sq[row] = s;
        wsq += (double)s;

        const __half h0 = __float2half(v.x), h1 = __float2half(v.y);
        const __half h2 = __float2half(v.z), h3 = __float2half(v.w);
        uint2 q;
        q.x = (uint32_t)(*(const unsigned short*)&h0)
            | ((uint32_t)(*(const unsigned short*)&h1) << 16);
        q.y = (uint32_t)(*(const unsigned short*)&h2)
            | ((uint32_t)(*(const unsigned short*)&h3) << 16);
        const int p  = row >> 7;
        const int rp = row & 127;
        const size_t off_b = (((size_t)(kt * 64 + p)) << 13)
                           + (size_t)u * 2048 + (size_t)rp * 16 + (size_t)half * 8;
        *(uint2*)(xh + off_b) = q;
    }
    __shared__ double cp[4][256];
    __shared__ double sqw[4];
    cp[w][lane * 4 + 0] = ca0;
    cp[w][lane * 4 + 1] = ca1;
    cp[w][lane * 4 + 2] = ca2;
    cp[w][lane * 4 + 3] = ca3;
    if (lane == 0) sqw[w] = wsq;
    __syncthreads();
    colpart[b * 256 + tid] = cp[0][tid] + cp[1][tid] + cp[2][tid] + cp[3][tid];
    if (tid == 0) sqpart[b] = sqw[0] + sqw[1] + sqw[2] + sqw[3];
}

// ---------------------------------------------------------------------------
// bandwidth: analytic fp64 sum(L2) = 2n*sum(sq) - 2*||sum_i x_i||^2.
// Stores the single exp2 coefficient for the SMALLEST-coefficient kernel:
// coef[0] = -log2(e) / (bandwidth * 16); the other 4 terms come from squaring.
// ---------------------------------------------------------------------------
__global__ __launch_bounds__(256) void bandwidth_kernel(
    const double* __restrict__ colpart, const double* __restrict__ sqpart,
    float* __restrict__ coef)
{
    const int tid = threadIdx.x;
    double cs = 0.0;
    for (int b = 0; b < 128; ++b) cs += colpart[b * 256 + tid];
    double v = cs * cs;
    #pragma unroll
    for (int off = 32; off; off >>= 1) v += __shfl_xor(v, off, 64);
    __shared__ double part[4];
    if ((tid & 63) == 0) part[tid >> 6] = v;
    __syncthreads();
    if (tid == 0) {
        const double s2 = part[0] + part[1] + part[2] + part[3];
        double sumsq = 0.0;
        for (int b = 0; b < 128; ++b) sumsq += sqpart[b];
        const double n = (double)NTOT;
        const double bwsum = 2.0 * n * sumsq - 2.0 * s2;
        double bandwidth = bwsum / (n * n - n);
        bandwidth *= 0.25;                       // / KERNEL_MUL^(NUM//2)
        const double LOG2E = 1.4426950408889634;
        coef[0] = (float)(-LOG2E / (bandwidth * 16.0));
    }
}

// ---------------------------------------------------------------------------
// main: triangular 128x128 tiles, register-direct fp16 MFMA (no LDS, no
// barriers in the K loop). 4 waves per block, each owns a 64x64 sub-tile.
// Epilogue: y = exp2(-L2*c4); kernel sum = y + y^2 + y^4 + y^8 + y^16.
// ---------------------------------------------------------------------------
__global__ __launch_bounds__(256) void mmd_main_kernel(
    const char* __restrict__ xh, const float* __restrict__ sq,
    const float* __restrict__ coef, double* __restrict__ quadpart)
{
    // bijective XCD-chunked swizzle: 2080 = 8 * 260
    const int bid = blockIdx.x;
    const int swz = (bid & 7) * 260 + (bid >> 3);
    // triangular decode: C(r) = 64r - r(r-1)/2 blocks before row r
    int by = (int)((129.0 - sqrt((double)(16641 - 8 * swz))) * 0.5);
    if (by < 0) by = 0;
    while ((by + 1) * 64 - ((by + 1) * by) / 2 <= swz) ++by;
    while (by * 64 - (by * (by - 1)) / 2 > swz) --by;
    const int bx = by + (swz - (by * 64 - (by * (by - 1)) / 2));

    const int tid  = threadIdx.x;
    const int w    = tid >> 6;
    const int lane = tid & 63;
    const int wr   = w >> 1, wc = w & 1;       // 2x2 wave grid, 64x64 each
    const int grp  = lane >> 4;                 // k-slot 0..3
    const int r16  = lane & 15;

    const float negc = coef[0];
    const char* pA = xh + (((size_t)by) << 13) + (size_t)grp * 2048
                   + (size_t)(wr * 64 + r16) * 16;
    const char* pB = xh + (((size_t)bx) << 13) + (size_t)grp * 2048
                   + (size_t)(wc * 64 + r16) * 16;

    f32x4 acc[4][4];
    #pragma unroll
    for (int m = 0; m < 4; ++m)
        #pragma unroll
        for (int n = 0; n < 4; ++n)
            acc[m][n] = (f32x4){0.0f, 0.0f, 0.0f, 0.0f};

    #pragma unroll
    for (int kt = 0; kt < 8; ++kt) {
        short8v a[4], b[4];
        #pragma unroll
        for (int m = 0; m < 4; ++m)
            a[m] = *(const short8v*)(pA + (size_t)kt * 524288 + m * 256);
        #pragma unroll
        for (int n = 0; n < 4; ++n)
            b[n] = *(const short8v*)(pB + (size_t)kt * 524288 + n * 256);
        #pragma unroll
        for (int m = 0; m < 4; ++m)
            #pragma unroll
            for (int n = 0; n < 4; ++n)
                acc[m][n] = __builtin_amdgcn_mfma_f32_16x16x32_f16(a[m], b[n], acc[m][n], 0, 0, 0);
    }

    // epilogue. C layout: col = lane&15 (B/n side), row = grp*4 + reg (A/m side)
    double kd = 0.0;
    #pragma unroll
    for (int m = 0; m < 4; ++m) {
        float sqa[4];
        #pragma unroll
        for (int r = 0; r < 4; ++r)
            sqa[r] = sq[by * 128 + wr * 64 + m * 16 + grp * 4 + r];
        #pragma unroll
        for (int n = 0; n < 4; ++n) {
            const float sqb = sq[bx * 128 + wc * 64 + n * 16 + r16];
            float ks = 0.0f;
            #pragma unroll
            for (int r = 0; r < 4; ++r) {
                const float l2 = fmaxf(fmaf(-2.0f, acc[m][n][r], sqa[r] + sqb), 0.0f);
                const float y  = __builtin_amdgcn_exp2f(l2 * negc);
                const float y2 = y * y, y4 = y2 * y2, y8 = y4 * y4, y16 = y8 * y8;
                ks += (y + y2) + (y4 + y8) + y16;
            }
            kd += (double)ks;
        }
    }
    #pragma unroll
    for (int off = 32; off; off >>= 1) kd += __shfl_xor(kd, off, 64);
    __shared__ double wpart[4];
    if (lane == 0) wpart[w] = kd;
    __syncthreads();
    if (tid == 0) {
        const double s = wpart[0] + wpart[1] + wpart[2] + wpart[3];
        quadpart[by * 64 + bx] = s;
        if (bx > by) quadpart[bx * 64 + by] = s;     // mirror block
    }
}

// ---------------------------------------------------------------------------
// finalize: reduce 64x64 block partials into the quadrant combination.
// ---------------------------------------------------------------------------
__global__ __launch_bounds__(256) void finalize_kernel(
    const double* __restrict__ quadpart, float* __restrict__ out)
{
    const int tid = threadIdx.x;
    double acc[4] = {0.0, 0.0, 0.0, 0.0};
    for (int i = tid; i < 4096; i += 256) {
        const int by = i >> 6, bx = i & 63;
        const int q = ((by >= 32) ? 2 : 0) + ((bx >= 32) ? 1 : 0);
        acc[q] += quadpart[i];
    }
    #pragma unroll
    for (int q = 0; q < 4; ++q)
        #pragma unroll
        for (int off = 32; off; off >>= 1) acc[q] += __shfl_xor(acc[q], off, 64);
    __shared__ double part[4][4];
    const int w = tid >> 6, lane = tid & 63;
    if (lane == 0) {
        #pragma unroll
        for (int q = 0; q < 4; ++q) part[w][q] = acc[q];
    }
    __syncthreads();
    if (tid == 0) {
        double s[4];
        #pragma unroll
        for (int q = 0; q < 4; ++q) s[q] = part[0][q] + part[1][q] + part[2][q] + part[3][q];
        const double denom = (double)N_S * (double)N_S;
        out[0] = (float)((s[0] + s[3] - s[1] - s[2]) / denom);
    }
}

extern "C" void kernel_launch(void* const* d_in, const int* in_sizes, int n_in,
                              void* d_out, int out_size, void* d_ws, size_t ws_size,
                              hipStream_t stream)
{
    const float* src = (const float*)d_in[0];
    const float* tgt = (const float*)d_in[1];
    float*  out      = (float*)d_out;
    char*   ws       = (char*)d_ws;

    float*  sq       = (float*)(ws + WS_SQ);
    double* colpart  = (double*)(ws + WS_COLPART);
    double* sqpart   = (double*)(ws + WS_SQPART);
    float*  coef     = (float*)(ws + WS_COEF);
    double* quadpart = (double*)(ws + WS_QUADPART);
    char*   xh       = ws + WS_XH;

    prep_kernel<<<128, 256, 0, stream>>>(src, tgt, sq, colpart, sqpart, xh);
    bandwidth_kernel<<<1, 256, 0, stream>>>(colpart, sqpart, coef);
    mmd_main_kernel<<<NBLK, 256, 0, stream>>>(xh, sq, coef, quadpart);
    finalize_kernel<<<1, 256, 0, stream>>>(quadpart, out);
}